// Round 1
// baseline (2082.354 us; speedup 1.0000x reference)
//
#include <hip/hip_runtime.h>

#define TT  65536      // B*T
#define R2  16384      // RESO*RESO
#define HID 128
#define PPB 16         // points per block in MLP kernels

// ---- ordered-uint encoding for float atomicMax ----
__device__ __forceinline__ unsigned f2o(float x){
    unsigned u = __float_as_uint(x);
    return (u & 0x80000000u) ? ~u : (u | 0x80000000u);
}
__device__ __forceinline__ float o2f(unsigned o){
    unsigned u = (o & 0x80000000u) ? (o ^ 0x80000000u) : ~o;
    return __uint_as_float(u);
}
__device__ __forceinline__ float nrm(float a){
    float v = a / 1.101f + 0.5f;
    v = fmaxf(v, 0.0f);
    v = fminf(v, 0.99999f);   // 1 - 1e-5 rounded to f32
    return v;
}

// ---- per-point plane cell indices ----
__global__ __launch_bounds__(256) void k_idx(const float* __restrict__ p, int* __restrict__ idx){
    int pt = blockIdx.x*256 + threadIdx.x;
    if (pt >= TT) return;
    float p0 = p[pt*3+0], p1 = p[pt*3+1], p2 = p[pt*3+2];
    int g0 = (int)(nrm(p0)*128.f);
    int g1 = (int)(nrm(p1)*128.f);
    int g2 = (int)(nrm(p2)*128.f);
    idx[0*TT + pt] = g0 + 128*g2;   // xz: dims (0,2)
    idx[1*TT + pt] = g0 + 128*g1;   // xy: dims (0,1)
    idx[2*TT + pt] = g1 + 128*g2;   // yz: dims (1,2)
}

// ---- fc_pos: net0 = p @ W(3x256) + b ----
__global__ __launch_bounds__(256) void k_fcpos(const float* __restrict__ p,
        const float* __restrict__ W, const float* __restrict__ b,
        float* __restrict__ xbuf){
    int pt = blockIdx.x;
    int j  = threadIdx.x;
    float p0 = p[pt*3+0], p1 = p[pt*3+1], p2 = p[pt*3+2];
    xbuf[(size_t)pt*256 + j] = b[j] + p0*W[j] + p1*W[256+j] + p2*W[512+j];
}

// ---- fused ResnetBlockFC: x(256) -> out(128), out written to xbuf[:,0:128] ----
__global__ __launch_bounds__(128) void k_resnet(float* __restrict__ xbuf,
        const float* __restrict__ W0, const float* __restrict__ b0,
        const float* __restrict__ W1, const float* __restrict__ b1,
        const float* __restrict__ Ws){
    __shared__ float lx[256*PPB];   // raw x, k-major [k][p]
    __shared__ float lr[256*PPB];   // relu(x); first 128*PPB reused as netk after stage1
    int t = threadIdx.x;
    size_t base = (size_t)blockIdx.x * PPB * 256;

    #pragma unroll
    for (int i = 0; i < 32; i++){
        int lin = i*128 + t;           // lin = p*256 + k
        float v = xbuf[base + lin];
        int pp = lin >> 8, k = lin & 255;
        lx[k*PPB+pp] = v;
        lr[k*PPB+pp] = fmaxf(v, 0.f);
    }
    __syncthreads();

    // stage 1: net = relu(x) @ W0 + b0
    float acc[PPB];
    #pragma unroll
    for (int q = 0; q < PPB; q++) acc[q] = 0.f;
    #pragma unroll 2
    for (int k = 0; k < 256; k++){
        float w = W0[k*HID + t];
        const float4* v4 = (const float4*)&lr[k*PPB];
        #pragma unroll
        for (int q = 0; q < PPB/4; q++){
            float4 v = v4[q];
            acc[4*q+0] = fmaf(v.x, w, acc[4*q+0]);
            acc[4*q+1] = fmaf(v.y, w, acc[4*q+1]);
            acc[4*q+2] = fmaf(v.z, w, acc[4*q+2]);
            acc[4*q+3] = fmaf(v.w, w, acc[4*q+3]);
        }
    }
    float bb0 = b0[t];
    __syncthreads();   // all stage-1 reads of lr done before overwrite
    // thread t owns feature t: write relu(net) k-major into lr (netk[128][PPB])
    #pragma unroll
    for (int q = 0; q < PPB/4; q++){
        float4 v;
        v.x = fmaxf(acc[4*q+0]+bb0, 0.f);
        v.y = fmaxf(acc[4*q+1]+bb0, 0.f);
        v.z = fmaxf(acc[4*q+2]+bb0, 0.f);
        v.w = fmaxf(acc[4*q+3]+bb0, 0.f);
        ((float4*)&lr[t*PPB])[q] = v;
    }
    __syncthreads();

    // stage 2: dx = relu(net) @ W1 (+b1 later)
    float dx[PPB];
    #pragma unroll
    for (int q = 0; q < PPB; q++) dx[q] = 0.f;
    #pragma unroll 2
    for (int k = 0; k < 128; k++){
        float w = W1[k*HID + t];
        const float4* v4 = (const float4*)&lr[k*PPB];
        #pragma unroll
        for (int q = 0; q < PPB/4; q++){
            float4 v = v4[q];
            dx[4*q+0] = fmaf(v.x, w, dx[4*q+0]);
            dx[4*q+1] = fmaf(v.y, w, dx[4*q+1]);
            dx[4*q+2] = fmaf(v.z, w, dx[4*q+2]);
            dx[4*q+3] = fmaf(v.w, w, dx[4*q+3]);
        }
    }

    // stage 3: shortcut x @ Ws
    #pragma unroll
    for (int q = 0; q < PPB; q++) acc[q] = 0.f;
    #pragma unroll 2
    for (int k = 0; k < 256; k++){
        float w = Ws[k*HID + t];
        const float4* v4 = (const float4*)&lx[k*PPB];
        #pragma unroll
        for (int q = 0; q < PPB/4; q++){
            float4 v = v4[q];
            acc[4*q+0] = fmaf(v.x, w, acc[4*q+0]);
            acc[4*q+1] = fmaf(v.y, w, acc[4*q+1]);
            acc[4*q+2] = fmaf(v.z, w, acc[4*q+2]);
            acc[4*q+3] = fmaf(v.w, w, acc[4*q+3]);
        }
    }
    float bb1 = b1[t];
    #pragma unroll
    for (int q = 0; q < PPB; q++)
        xbuf[base + q*256 + t] = acc[q] + dx[q] + bb1;
}

// ---- fc_c: c = net @ W(128x128) + b, written to xbuf[:,128:256] ----
__global__ __launch_bounds__(128) void k_fcc(float* __restrict__ xbuf,
        const float* __restrict__ W, const float* __restrict__ b){
    __shared__ float ln[HID*PPB];   // k-major [k][p]
    int t = threadIdx.x;
    size_t base = (size_t)blockIdx.x * PPB * 256;
    #pragma unroll
    for (int i = 0; i < PPB; i++){
        // element (p=i, k=t)
        ln[t*PPB + i] = xbuf[base + (size_t)i*256 + t];
    }
    __syncthreads();
    float acc[PPB];
    #pragma unroll
    for (int q = 0; q < PPB; q++) acc[q] = 0.f;
    #pragma unroll 2
    for (int k = 0; k < HID; k++){
        float w = W[k*HID + t];
        const float4* v4 = (const float4*)&ln[k*PPB];
        #pragma unroll
        for (int q = 0; q < PPB/4; q++){
            float4 v = v4[q];
            acc[4*q+0] = fmaf(v.x, w, acc[4*q+0]);
            acc[4*q+1] = fmaf(v.y, w, acc[4*q+1]);
            acc[4*q+2] = fmaf(v.z, w, acc[4*q+2]);
            acc[4*q+3] = fmaf(v.w, w, acc[4*q+3]);
        }
    }
    float bb = b[t];
    #pragma unroll
    for (int q = 0; q < PPB; q++)
        xbuf[base + q*256 + 128 + t] = acc[q] + bb;
}

// ---- scatter-max into 3 planes ----
__global__ __launch_bounds__(256) void k_scmax(const float* __restrict__ xbuf,
        const int* __restrict__ idx, unsigned* __restrict__ mx){
    int g = blockIdx.x*256 + threadIdx.x;
    int pt = g >> 7, f = g & 127;
    int b = pt >> 15;
    unsigned o = f2o(xbuf[(size_t)pt*256 + f]);
    #pragma unroll
    for (int pl = 0; pl < 3; pl++){
        int cell = idx[pl*TT + pt];
        atomicMax(&mx[(((size_t)(pl*2 + b) << 14) + cell)*128 + f], o);
    }
}

// ---- gather pooled = sum of plane maxima -> xbuf[:,128:256] ----
__global__ __launch_bounds__(256) void k_gather(float* __restrict__ xbuf,
        const int* __restrict__ idx, const unsigned* __restrict__ mx){
    int g = blockIdx.x*256 + threadIdx.x;
    int pt = g >> 7, f = g & 127;
    int b = pt >> 15;
    float s = 0.f;
    #pragma unroll
    for (int pl = 0; pl < 3; pl++){
        int cell = idx[pl*TT + pt];
        s += o2f(mx[(((size_t)(pl*2 + b) << 14) + cell)*128 + f]);
    }
    xbuf[(size_t)pt*256 + 128 + f] = s;
}

// ---- scatter-mean sums ----
__global__ __launch_bounds__(256) void k_scmean(const float* __restrict__ xbuf,
        const int* __restrict__ idx, float* __restrict__ sum){
    int g = blockIdx.x*256 + threadIdx.x;
    int pt = g >> 7, f = g & 127;
    int b = pt >> 15;
    float c = xbuf[(size_t)pt*256 + 128 + f];
    #pragma unroll
    for (int pl = 0; pl < 3; pl++){
        int cell = idx[pl*TT + pt];
        atomicAdd(&sum[(((size_t)(pl*2 + b) << 14) + cell)*128 + f], c);
    }
}

__global__ __launch_bounds__(256) void k_cnt(const int* __restrict__ idx, float* __restrict__ cnt){
    int pt = blockIdx.x*256 + threadIdx.x;
    if (pt >= TT) return;
    int b = pt >> 15;
    #pragma unroll
    for (int pl = 0; pl < 3; pl++)
        atomicAdd(&cnt[((pl*2 + b) << 14) + idx[pl*TT + pt]], 1.f);
}

// ---- finalize: out[pb][f][cell] = sum[pb][cell][f] / max(cnt,1) (transpose) ----
__global__ __launch_bounds__(256) void k_final(const float* __restrict__ sum,
        const float* __restrict__ cnt, float* __restrict__ out){
    __shared__ float ls[32][33];
    int pb = blockIdx.z;
    const float* s  = sum + (size_t)pb*R2*HID;
    const float* cn = cnt + (size_t)pb*R2;
    float* o = out + (size_t)pb*HID*R2;
    int c0 = blockIdx.x*32, f0 = blockIdx.y*32;
    int tx = threadIdx.x, ty = threadIdx.y;
    #pragma unroll
    for (int j = 0; j < 4; j++){
        int row = ty + j*8;                          // cell offset
        float rc = 1.f / fmaxf(cn[c0+row], 1.f);
        ls[row][tx] = s[(size_t)(c0+row)*HID + f0+tx] * rc;
    }
    __syncthreads();
    #pragma unroll
    for (int j = 0; j < 4; j++){
        int row = ty + j*8;                          // feature offset
        o[(size_t)(f0+row)*R2 + c0+tx] = ls[tx][row];
    }
}

extern "C" void kernel_launch(void* const* d_in, const int* in_sizes, int n_in,
                              void* d_out, int out_size, void* d_ws, size_t ws_size,
                              hipStream_t stream) {
    const float* p        = (const float*)d_in[0];
    const float* fc_pos_W = (const float*)d_in[1];
    const float* fc_pos_b = (const float*)d_in[2];
    const float* bW0      = (const float*)d_in[3];
    const float* bb0      = (const float*)d_in[4];
    const float* bW1      = (const float*)d_in[5];
    const float* bb1      = (const float*)d_in[6];
    const float* bWs      = (const float*)d_in[7];
    const float* fc_c_W   = (const float*)d_in[8];
    const float* fc_c_b   = (const float*)d_in[9];
    float* out = (float*)d_out;

    char* ws = (char*)d_ws;
    int*   idx  = (int*)ws;                                  // 3*TT ints
    float* xbuf = (float*)(ws + (size_t)3*TT*4);             // TT x 256 f32
    size_t offP = (size_t)3*TT*4 + (size_t)TT*256*4;
    unsigned* mx  = (unsigned*)(ws + offP);                  // 6*R2*128 u32 (reused as sum)
    float*    sum = (float*)mx;
    float*    cnt = (float*)(ws + offP + (size_t)6*R2*128*4);// 6*R2 f32

    k_idx  <<<TT/256, 256, 0, stream>>>(p, idx);
    k_fcpos<<<TT, 256, 0, stream>>>(p, fc_pos_W, fc_pos_b, xbuf);
    k_resnet<<<TT/PPB, 128, 0, stream>>>(xbuf, bW0, bb0, bW1, bb1, bWs);

    for (int i = 1; i < 5; i++){
        hipMemsetAsync(mx, 0, (size_t)6*R2*128*4, stream);
        k_scmax <<<TT*128/256, 256, 0, stream>>>(xbuf, idx, mx);
        k_gather<<<TT*128/256, 256, 0, stream>>>(xbuf, idx, mx);
        k_resnet<<<TT/PPB, 128, 0, stream>>>(xbuf,
                bW0 + (size_t)i*256*128, bb0 + (size_t)i*128,
                bW1 + (size_t)i*128*128, bb1 + (size_t)i*128,
                bWs + (size_t)i*256*128);
    }

    k_fcc<<<TT/PPB, 128, 0, stream>>>(xbuf, fc_c_W, fc_c_b);

    hipMemsetAsync(sum, 0, (size_t)6*R2*128*4, stream);
    hipMemsetAsync(cnt, 0, (size_t)6*R2*4, stream);
    k_scmean<<<TT*128/256, 256, 0, stream>>>(xbuf, idx, sum);
    k_cnt   <<<TT/256, 256, 0, stream>>>(idx, cnt);

    dim3 fb(32,8), fg(R2/32, HID/32, 6);
    k_final<<<fg, fb, 0, stream>>>(sum, cnt, out);
}

// Round 2
// 938.292 us; speedup vs baseline: 2.2193x; 2.2193x over previous
//
#include <hip/hip_runtime.h>

#define TT 65536
#define R2 16384

typedef _Float16 f16x8 __attribute__((ext_vector_type(8)));
typedef float    f32x4 __attribute__((ext_vector_type(4)));
typedef unsigned u32x4 __attribute__((ext_vector_type(4)));

#define MFMA16 __builtin_amdgcn_mfma_f32_16x16x32_f16

// ---- helpers ----
__device__ __forceinline__ unsigned short f2h(float f){
    _Float16 h = (_Float16)f;                  // v_cvt_f16_f32, RNE
    return __builtin_bit_cast(unsigned short, h);
}
__device__ __forceinline__ float h2f(unsigned short u){
    return (float)__builtin_bit_cast(_Float16, u);
}
// packed relu on 2 f16 halves: clear halves with sign bit set
__device__ __forceinline__ unsigned relu2(unsigned w){
    unsigned s = w & 0x80008000u;
    unsigned mask = ((s >> 15) * 0x7FFFu) | s; // 0xFFFF per negative half
    return w & ~mask;
}
// ordered-uint encoding for float atomicMax
__device__ __forceinline__ unsigned f2o(float x){
    unsigned u = __float_as_uint(x);
    return (u & 0x80000000u) ? ~u : (u | 0x80000000u);
}
__device__ __forceinline__ float o2f(unsigned o){
    unsigned u = (o & 0x80000000u) ? (o ^ 0x80000000u) : ~o;
    return __uint_as_float(u);
}
__device__ __forceinline__ float nrm(float a){
    float v = a / 1.101f + 0.5f;
    v = fmaxf(v, 0.0f);
    v = fminf(v, 0.99999f);
    return v;
}

// ---- repack all weights f32 -> f16 in B-fragment-swizzled layout ----
// per GEMM weight (K x 128): packed[((ks*8+t)*64+lane)*8+j] = W[ks*32+(lane>>4)*8+j][t*16+(lane&15)]
// wpack layout (f16 elems): per block i (i<5): W0p @ i*81920, W1p @ +32768, Wsp @ +49152; fc_cp @ 409600
__global__ __launch_bounds__(256) void k_repack(const float* __restrict__ W0,
        const float* __restrict__ W1, const float* __restrict__ Ws,
        const float* __restrict__ Wc, unsigned short* __restrict__ out){
    int e = blockIdx.x*256 + threadIdx.x;      // 0..425983
    const float* src; int r;
    if (e < 409600){
        int i = e / 81920; r = e % 81920;
        if (r < 32768)      { src = W0 + (size_t)i*32768; }
        else if (r < 49152) { src = W1 + (size_t)i*16384; r -= 32768; }
        else                { src = Ws + (size_t)i*32768; r -= 49152; }
    } else { src = Wc; r = e - 409600; }
    int j = r & 7, l = (r >> 3) & 63, t = (r >> 9) & 7, ks = r >> 12;
    int k = ks*32 + (l >> 4)*8 + j;
    int n = t*16 + (l & 15);
    out[e] = f2h(src[k*128 + n]);
}

// ---- per-point plane cell indices ----
__global__ __launch_bounds__(256) void k_idx(const float* __restrict__ p, int* __restrict__ idx){
    int pt = blockIdx.x*256 + threadIdx.x;
    if (pt >= TT) return;
    float p0 = p[pt*3+0], p1 = p[pt*3+1], p2 = p[pt*3+2];
    int g0 = (int)(nrm(p0)*128.f);
    int g1 = (int)(nrm(p1)*128.f);
    int g2 = (int)(nrm(p2)*128.f);
    idx[0*TT + pt] = g0 + 128*g2;
    idx[1*TT + pt] = g0 + 128*g1;
    idx[2*TT + pt] = g1 + 128*g2;
}

// ---- fc_pos: net0 = p @ W(3x256) + b, stored f16 ----
__global__ __launch_bounds__(256) void k_fcpos(const float* __restrict__ p,
        const float* __restrict__ W, const float* __restrict__ b,
        unsigned short* __restrict__ xb){
    int pt = blockIdx.x;
    int j  = threadIdx.x;
    float p0 = p[pt*3+0], p1 = p[pt*3+1], p2 = p[pt*3+2];
    float v = b[j] + p0*W[j] + p1*W[256+j] + p2*W[512+j];
    xb[(size_t)pt*256 + j] = f2h(v);
}

// ---- fused ResnetBlockFC via MFMA: x(256,f16 raw) -> out(128) into xb cols 0..127 ----
__global__ __launch_bounds__(256) void k_resnet(unsigned short* __restrict__ xb,
        const unsigned short* __restrict__ wp,
        const float* __restrict__ b0, const float* __restrict__ b1){
    __shared__ __align__(16) unsigned short lds[32768];  // 64KB: lw 32KB + lt 32KB
    unsigned short* lw = lds;
    unsigned short* lt = lds + 16384;
    int tid = threadIdx.x, w = tid >> 6, lane = tid & 63;
    int quad = lane >> 4, l15 = lane & 15;
    int m0 = blockIdx.x*128 + w*32;
    float b0v[8], b1v[8];
    #pragma unroll
    for (int t = 0; t < 8; t++){ b0v[t] = b0[t*16 + l15]; b1v[t] = b1[t*16 + l15]; }
    const size_t row0 = (size_t)(m0 + l15)*256;
    const size_t row1 = row0 + 16*256;

    f32x4 acc[2][8];
    #pragma unroll
    for (int s = 0; s < 2; s++)
        #pragma unroll
        for (int t = 0; t < 8; t++){ f32x4 z = {0.f,0.f,0.f,0.f}; acc[s][t] = z; }

    // ---- GEMM1: relu(x) @ W0  (K=256, two 32KB weight chunks) ----
    for (int c = 0; c < 2; c++){
        __syncthreads();
        { const u32x4* g = (const u32x4*)(wp + c*16384); u32x4* l = (u32x4*)lw;
          #pragma unroll
          for (int i = 0; i < 8; i++) l[i*256 + tid] = g[i*256 + tid]; }
        __syncthreads();
        #pragma unroll
        for (int ks = 0; ks < 4; ks++){
            int ko = (c*4 + ks)*32 + quad*8;
            u32x4 u0 = *(const u32x4*)(xb + row0 + ko);
            u32x4 u1 = *(const u32x4*)(xb + row1 + ko);
            u0.x = relu2(u0.x); u0.y = relu2(u0.y); u0.z = relu2(u0.z); u0.w = relu2(u0.w);
            u1.x = relu2(u1.x); u1.y = relu2(u1.y); u1.z = relu2(u1.z); u1.w = relu2(u1.w);
            f16x8 a0 = __builtin_bit_cast(f16x8, u0);
            f16x8 a1 = __builtin_bit_cast(f16x8, u1);
            #pragma unroll
            for (int t = 0; t < 8; t++){
                f16x8 b = *(const f16x8*)&lw[((ks*8 + t)*64 + lane)*8];
                acc[0][t] = MFMA16(a0, b, acc[0][t], 0, 0, 0);
                acc[1][t] = MFMA16(a1, b, acc[1][t], 0, 0, 0);
            }
        }
    }

    // ---- transform: relu(net+b0) -> lt in A-fragment layout (own-wave strips only) ----
    #pragma unroll
    for (int s = 0; s < 2; s++){
        int strip = w*2 + s;
        #pragma unroll
        for (int t = 0; t < 8; t++){
            int ks2 = t >> 1;
            int l2b = ((t & 1)*2 + ((lane >> 3) & 1))*16 + quad*4;
            #pragma unroll
            for (int r = 0; r < 4; r++){
                float v = acc[s][t][r] + b0v[t];
                v = fmaxf(v, 0.f);
                lt[(((ks2*8 + strip)*64) + l2b + r)*8 + (lane & 7)] = f2h(v);
            }
        }
    }

    // ---- GEMM2: relu(net) @ W1 (K=128), acc init = b1 ----
    __syncthreads();
    { const u32x4* g = (const u32x4*)(wp + 32768); u32x4* l = (u32x4*)lw;
      #pragma unroll
      for (int i = 0; i < 8; i++) l[i*256 + tid] = g[i*256 + tid]; }
    __syncthreads();
    f32x4 acc2[2][8];
    #pragma unroll
    for (int s = 0; s < 2; s++)
        #pragma unroll
        for (int t = 0; t < 8; t++){ f32x4 iv = {b1v[t],b1v[t],b1v[t],b1v[t]}; acc2[s][t] = iv; }
    #pragma unroll
    for (int ks = 0; ks < 4; ks++){
        f16x8 a0 = *(const f16x8*)&lt[((ks*8 + w*2 + 0)*64 + lane)*8];
        f16x8 a1 = *(const f16x8*)&lt[((ks*8 + w*2 + 1)*64 + lane)*8];
        #pragma unroll
        for (int t = 0; t < 8; t++){
            f16x8 b = *(const f16x8*)&lw[((ks*8 + t)*64 + lane)*8];
            acc2[0][t] = MFMA16(a0, b, acc2[0][t], 0, 0, 0);
            acc2[1][t] = MFMA16(a1, b, acc2[1][t], 0, 0, 0);
        }
    }

    // ---- GEMM3: shortcut x @ Ws (K=256), accumulate into acc2 ----
    for (int c = 0; c < 2; c++){
        __syncthreads();
        { const u32x4* g = (const u32x4*)(wp + 49152 + c*16384); u32x4* l = (u32x4*)lw;
          #pragma unroll
          for (int i = 0; i < 8; i++) l[i*256 + tid] = g[i*256 + tid]; }
        __syncthreads();
        #pragma unroll
        for (int ks = 0; ks < 4; ks++){
            int ko = (c*4 + ks)*32 + quad*8;
            f16x8 a0 = *(const f16x8*)(xb + row0 + ko);
            f16x8 a1 = *(const f16x8*)(xb + row1 + ko);
            #pragma unroll
            for (int t = 0; t < 8; t++){
                f16x8 b = *(const f16x8*)&lw[((ks*8 + t)*64 + lane)*8];
                acc2[0][t] = MFMA16(a0, b, acc2[0][t], 0, 0, 0);
                acc2[1][t] = MFMA16(a1, b, acc2[1][t], 0, 0, 0);
            }
        }
    }

    // ---- epilogue: out = x@Ws + dx + b1 -> xb cols 0..127 (f16) ----
    #pragma unroll
    for (int s = 0; s < 2; s++)
        #pragma unroll
        for (int t = 0; t < 8; t++)
            #pragma unroll
            for (int r = 0; r < 4; r++){
                int row = m0 + s*16 + quad*4 + r;
                xb[(size_t)row*256 + t*16 + l15] = f2h(acc2[s][t][r]);
            }
}

// ---- fc_c via MFMA + fused scatter-mean atomics ----
__global__ __launch_bounds__(256) void k_fcc(const unsigned short* __restrict__ xb,
        const unsigned short* __restrict__ wcp, const float* __restrict__ bc,
        const int* __restrict__ idx, float* __restrict__ sum){
    int tid = threadIdx.x, w = tid >> 6, lane = tid & 63;
    int quad = lane >> 4, l15 = lane & 15;
    int m0 = blockIdx.x*128 + w*32;
    float bv[8];
    #pragma unroll
    for (int t = 0; t < 8; t++) bv[t] = bc[t*16 + l15];
    f32x4 acc[2][8];
    #pragma unroll
    for (int s = 0; s < 2; s++)
        #pragma unroll
        for (int t = 0; t < 8; t++){ f32x4 iv = {bv[t],bv[t],bv[t],bv[t]}; acc[s][t] = iv; }
    const size_t row0 = (size_t)(m0 + l15)*256;
    const size_t row1 = row0 + 16*256;
    #pragma unroll
    for (int ks = 0; ks < 4; ks++){
        int ko = ks*32 + quad*8;
        f16x8 a0 = *(const f16x8*)(xb + row0 + ko);
        f16x8 a1 = *(const f16x8*)(xb + row1 + ko);
        #pragma unroll
        for (int t = 0; t < 8; t++){
            f16x8 b = *(const f16x8*)(wcp + ((ks*8 + t)*64 + lane)*8);
            acc[0][t] = MFMA16(a0, b, acc[0][t], 0, 0, 0);
            acc[1][t] = MFMA16(a1, b, acc[1][t], 0, 0, 0);
        }
    }
    // fused scatter-mean numerator (f32 atomics)
    #pragma unroll
    for (int s = 0; s < 2; s++)
        #pragma unroll
        for (int r = 0; r < 4; r++){
            int row = m0 + s*16 + quad*4 + r;
            int b = row >> 15;
            size_t p0 = ((size_t)(0 + b)*R2 + idx[row])*128;
            size_t p1 = ((size_t)(2 + b)*R2 + idx[TT + row])*128;
            size_t p2 = ((size_t)(4 + b)*R2 + idx[2*TT + row])*128;
            #pragma unroll
            for (int t = 0; t < 8; t++){
                float v = acc[s][t][r];
                int col = t*16 + l15;
                atomicAdd(&sum[p0 + col], v);
                atomicAdd(&sum[p1 + col], v);
                atomicAdd(&sum[p2 + col], v);
            }
        }
}

// ---- scatter-max (reads f16 net in xb cols 0..127) ----
__global__ __launch_bounds__(256) void k_scmax(const unsigned short* __restrict__ xb,
        const int* __restrict__ idx, unsigned* __restrict__ mx){
    int g = blockIdx.x*256 + threadIdx.x;   // over TT*64
    int pt = g >> 6, fp = g & 63;
    int b = pt >> 15;
    unsigned v = ((const unsigned*)(xb + (size_t)pt*256))[fp];
    unsigned o0 = f2o(h2f((unsigned short)(v & 0xFFFF)));
    unsigned o1 = f2o(h2f((unsigned short)(v >> 16)));
    #pragma unroll
    for (int pl = 0; pl < 3; pl++){
        int cell = idx[pl*TT + pt];
        size_t base = ((size_t)(pl*2 + b)*R2 + cell)*128 + fp*2;
        atomicMax(&mx[base],     o0);
        atomicMax(&mx[base + 1], o1);
    }
}

// ---- gather pooled = sum of 3 plane maxima -> xb cols 128..255 (f16) ----
__global__ __launch_bounds__(256) void k_gather(unsigned short* __restrict__ xb,
        const int* __restrict__ idx, const unsigned* __restrict__ mx){
    int g = blockIdx.x*256 + threadIdx.x;
    int pt = g >> 6, fp = g & 63;
    int b = pt >> 15;
    float s0 = 0.f, s1 = 0.f;
    #pragma unroll
    for (int pl = 0; pl < 3; pl++){
        int cell = idx[pl*TT + pt];
        const unsigned* q = &mx[((size_t)(pl*2 + b)*R2 + cell)*128 + fp*2];
        s0 += o2f(q[0]);
        s1 += o2f(q[1]);
    }
    unsigned outv = (unsigned)f2h(s0) | ((unsigned)f2h(s1) << 16);
    ((unsigned*)(xb + (size_t)pt*256 + 128))[fp] = outv;
}

__global__ __launch_bounds__(256) void k_cnt(const int* __restrict__ idx, float* __restrict__ cnt){
    int pt = blockIdx.x*256 + threadIdx.x;
    if (pt >= TT) return;
    int b = pt >> 15;
    #pragma unroll
    for (int pl = 0; pl < 3; pl++)
        atomicAdd(&cnt[((pl*2 + b) << 14) + idx[pl*TT + pt]], 1.f);
}

// ---- finalize: out[pb][f][cell] = sum[pb][cell][f] / max(cnt,1) ----
__global__ __launch_bounds__(256) void k_final(const float* __restrict__ sum,
        const float* __restrict__ cnt, float* __restrict__ out){
    __shared__ float ls[32][33];
    int pb = blockIdx.z;
    const float* s  = sum + (size_t)pb*R2*128;
    const float* cn = cnt + (size_t)pb*R2;
    float* o = out + (size_t)pb*128*R2;
    int c0 = blockIdx.x*32, f0 = blockIdx.y*32;
    int tx = threadIdx.x, ty = threadIdx.y;
    #pragma unroll
    for (int j = 0; j < 4; j++){
        int row = ty + j*8;
        float rc = 1.f / fmaxf(cn[c0 + row], 1.f);
        ls[row][tx] = s[(size_t)(c0 + row)*128 + f0 + tx] * rc;
    }
    __syncthreads();
    #pragma unroll
    for (int j = 0; j < 4; j++){
        int row = ty + j*8;
        o[(size_t)(f0 + row)*R2 + c0 + tx] = ls[tx][row];
    }
}

extern "C" void kernel_launch(void* const* d_in, const int* in_sizes, int n_in,
                              void* d_out, int out_size, void* d_ws, size_t ws_size,
                              hipStream_t stream) {
    const float* p        = (const float*)d_in[0];
    const float* fc_pos_W = (const float*)d_in[1];
    const float* fc_pos_b = (const float*)d_in[2];
    const float* bW0      = (const float*)d_in[3];
    const float* bb0      = (const float*)d_in[4];
    const float* bW1      = (const float*)d_in[5];
    const float* bb1      = (const float*)d_in[6];
    const float* bWs      = (const float*)d_in[7];
    const float* fc_c_W   = (const float*)d_in[8];
    const float* fc_c_b   = (const float*)d_in[9];
    float* out = (float*)d_out;

    char* ws = (char*)d_ws;
    int*            idx   = (int*)ws;                                   // 786,432 B
    unsigned short* xbuf  = (unsigned short*)(ws + 786432);             // 33,554,432 B
    unsigned*       mx    = (unsigned*)(ws + 786432 + 33554432);        // 50,331,648 B (mx / sum)
    float*          sum   = (float*)mx;
    float*          cnt   = (float*)(ws + 786432 + 33554432 + 50331648);// 393,216 B
    unsigned short* wpack = (unsigned short*)(ws + 786432 + 33554432 + 50331648 + 393216); // 851,968 B

    k_repack<<<1664, 256, 0, stream>>>(bW0, bW1, bWs, fc_c_W, wpack);
    k_idx   <<<TT/256, 256, 0, stream>>>(p, idx);
    k_fcpos <<<TT, 256, 0, stream>>>(p, fc_pos_W, fc_pos_b, xbuf);

    k_resnet<<<512, 256, 0, stream>>>(xbuf, wpack, bb0, bb1);
    for (int i = 1; i < 5; i++){
        hipMemsetAsync(mx, 0, (size_t)6*R2*128*4, stream);
        k_scmax <<<TT*64/256, 256, 0, stream>>>(xbuf, idx, mx);
        k_gather<<<TT*64/256, 256, 0, stream>>>(xbuf, idx, mx);
        k_resnet<<<512, 256, 0, stream>>>(xbuf, wpack + (size_t)i*81920,
                                          bb0 + (size_t)i*128, bb1 + (size_t)i*128);
    }

    hipMemsetAsync(sum, 0, (size_t)6*R2*128*4, stream);
    hipMemsetAsync(cnt, 0, (size_t)6*R2*4, stream);
    k_fcc<<<512, 256, 0, stream>>>(xbuf, wpack + 409600, fc_c_b, idx, sum);
    k_cnt<<<TT/256, 256, 0, stream>>>(idx, cnt);

    dim3 fb(32, 8), fg(R2/32, 128/32, 6);
    k_final<<<fg, fb, 0, stream>>>(sum, cnt, out);
}

// Round 3
// 724.546 us; speedup vs baseline: 2.8740x; 1.2950x over previous
//
#include <hip/hip_runtime.h>

#define TT 65536
#define R2 16384

typedef _Float16 f16x8 __attribute__((ext_vector_type(8)));
typedef float    f32x4 __attribute__((ext_vector_type(4)));
typedef unsigned u32x4 __attribute__((ext_vector_type(4)));

#define MFMA16 __builtin_amdgcn_mfma_f32_16x16x32_f16

// ---- helpers ----
__device__ __forceinline__ unsigned short f2h(float f){
    _Float16 h = (_Float16)f;
    return __builtin_bit_cast(unsigned short, h);
}
__device__ __forceinline__ float h2f(unsigned short u){
    return (float)__builtin_bit_cast(_Float16, u);
}
__device__ __forceinline__ unsigned relu2(unsigned w){
    unsigned s = w & 0x80008000u;
    unsigned mask = ((s >> 15) * 0x7FFFu) | s;
    return w & ~mask;
}
__device__ __forceinline__ float nrm(float a){
    float v = a / 1.101f + 0.5f;
    v = fmaxf(v, 0.0f);
    v = fminf(v, 0.99999f);
    return v;
}

// ---- repack weights f32 -> f16 B-fragment layout ----
__global__ __launch_bounds__(256) void k_repack(const float* __restrict__ W0,
        const float* __restrict__ W1, const float* __restrict__ Ws,
        const float* __restrict__ Wc, unsigned short* __restrict__ out){
    int e = blockIdx.x*256 + threadIdx.x;
    const float* src; int r;
    if (e < 409600){
        int i = e / 81920; r = e % 81920;
        if (r < 32768)      { src = W0 + (size_t)i*32768; }
        else if (r < 49152) { src = W1 + (size_t)i*16384; r -= 32768; }
        else                { src = Ws + (size_t)i*32768; r -= 49152; }
    } else { src = Wc; r = e - 409600; }
    int j = r & 7, l = (r >> 3) & 63, t = (r >> 9) & 7, ks = r >> 12;
    int k = ks*32 + (l >> 4)*8 + j;
    int n = t*16 + (l & 15);
    out[e] = f2h(src[k*128 + n]);
}

// ---- per-point plane cell indices ----
__global__ __launch_bounds__(256) void k_idx(const float* __restrict__ p, int* __restrict__ idx){
    int pt = blockIdx.x*256 + threadIdx.x;
    if (pt >= TT) return;
    float p0 = p[pt*3+0], p1 = p[pt*3+1], p2 = p[pt*3+2];
    int g0 = (int)(nrm(p0)*128.f);
    int g1 = (int)(nrm(p1)*128.f);
    int g2 = (int)(nrm(p2)*128.f);
    idx[0*TT + pt] = g0 + 128*g2;
    idx[1*TT + pt] = g0 + 128*g1;
    idx[2*TT + pt] = g1 + 128*g2;
}

// ---- counting sort: histogram ----
__global__ __launch_bounds__(256) void k_hist(const int* __restrict__ idx, int* __restrict__ cnt){
    int pt = blockIdx.x*256 + threadIdx.x;
    int b14 = (pt >> 15) << 14;
    #pragma unroll
    for (int pl = 0; pl < 3; pl++)
        atomicAdd(&cnt[pl*32768 + b14 + idx[pl*TT + pt]], 1);
}

// ---- counting sort: exclusive scan (1 block of 1024 per plane) ----
__global__ __launch_bounds__(1024) void k_scan(const int* __restrict__ cnt,
        int* __restrict__ cs, int* __restrict__ cp){
    __shared__ int ls[1024];
    int pl = blockIdx.x, tid = threadIdx.x;
    const int* c = cnt + pl*32768;
    int v[32], tot = 0;
    #pragma unroll
    for (int j = 0; j < 32; j++){ v[j] = c[tid*32 + j]; tot += v[j]; }
    int x = tot;
    ls[tid] = x; __syncthreads();
    for (int off = 1; off < 1024; off <<= 1){
        int add = (tid >= off) ? ls[tid - off] : 0;
        __syncthreads();
        x += add; ls[tid] = x;
        __syncthreads();
    }
    int run = x - tot;   // exclusive prefix of this thread's chunk
    #pragma unroll
    for (int j = 0; j < 32; j++){
        cs[pl*32769 + tid*32 + j] = run;
        cp[pl*32768 + tid*32 + j] = run;
        run += v[j];
    }
    if (tid == 1023) cs[pl*32769 + 32768] = TT;
}

// ---- counting sort: scatter point ids ----
__global__ __launch_bounds__(256) void k_scatter(const int* __restrict__ idx,
        int* __restrict__ cp, int* __restrict__ srt){
    int pt = blockIdx.x*256 + threadIdx.x;
    int b14 = (pt >> 15) << 14;
    #pragma unroll
    for (int pl = 0; pl < 3; pl++){
        int pos = atomicAdd(&cp[pl*32768 + b14 + idx[pl*TT + pt]], 1);
        srt[pl*TT + pos] = pt;
    }
}

// ---- fc_pos ----
__global__ __launch_bounds__(256) void k_fcpos(const float* __restrict__ p,
        const float* __restrict__ W, const float* __restrict__ b,
        unsigned short* __restrict__ xb){
    int pt = blockIdx.x;
    int j  = threadIdx.x;
    float p0 = p[pt*3+0], p1 = p[pt*3+1], p2 = p[pt*3+2];
    float v = b[j] + p0*W[j] + p1*W[256+j] + p2*W[512+j];
    xb[(size_t)pt*256 + j] = f2h(v);
}

// ---- fused ResnetBlockFC via MFMA ----
__global__ __launch_bounds__(256) void k_resnet(unsigned short* __restrict__ xb,
        const unsigned short* __restrict__ wp,
        const float* __restrict__ b0, const float* __restrict__ b1){
    __shared__ __align__(16) unsigned short lds[32768];
    unsigned short* lw = lds;
    unsigned short* lt = lds + 16384;
    int tid = threadIdx.x, w = tid >> 6, lane = tid & 63;
    int quad = lane >> 4, l15 = lane & 15;
    int m0 = blockIdx.x*128 + w*32;
    float b0v[8], b1v[8];
    #pragma unroll
    for (int t = 0; t < 8; t++){ b0v[t] = b0[t*16 + l15]; b1v[t] = b1[t*16 + l15]; }
    const size_t row0 = (size_t)(m0 + l15)*256;
    const size_t row1 = row0 + 16*256;

    f32x4 acc[2][8];
    #pragma unroll
    for (int s = 0; s < 2; s++)
        #pragma unroll
        for (int t = 0; t < 8; t++){ f32x4 z = {0.f,0.f,0.f,0.f}; acc[s][t] = z; }

    // GEMM1: relu(x) @ W0
    for (int c = 0; c < 2; c++){
        __syncthreads();
        { const u32x4* g = (const u32x4*)(wp + c*16384); u32x4* l = (u32x4*)lw;
          #pragma unroll
          for (int i = 0; i < 8; i++) l[i*256 + tid] = g[i*256 + tid]; }
        __syncthreads();
        #pragma unroll
        for (int ks = 0; ks < 4; ks++){
            int ko = (c*4 + ks)*32 + quad*8;
            u32x4 u0 = *(const u32x4*)(xb + row0 + ko);
            u32x4 u1 = *(const u32x4*)(xb + row1 + ko);
            u0.x = relu2(u0.x); u0.y = relu2(u0.y); u0.z = relu2(u0.z); u0.w = relu2(u0.w);
            u1.x = relu2(u1.x); u1.y = relu2(u1.y); u1.z = relu2(u1.z); u1.w = relu2(u1.w);
            f16x8 a0 = __builtin_bit_cast(f16x8, u0);
            f16x8 a1 = __builtin_bit_cast(f16x8, u1);
            #pragma unroll
            for (int t = 0; t < 8; t++){
                f16x8 b = *(const f16x8*)&lw[((ks*8 + t)*64 + lane)*8];
                acc[0][t] = MFMA16(a0, b, acc[0][t], 0, 0, 0);
                acc[1][t] = MFMA16(a1, b, acc[1][t], 0, 0, 0);
            }
        }
    }

    // transform relu(net+b0) -> A-fragment layout
    #pragma unroll
    for (int s = 0; s < 2; s++){
        int strip = w*2 + s;
        #pragma unroll
        for (int t = 0; t < 8; t++){
            int ks2 = t >> 1;
            int l2b = ((t & 1)*2 + ((lane >> 3) & 1))*16 + quad*4;
            #pragma unroll
            for (int r = 0; r < 4; r++){
                float v = acc[s][t][r] + b0v[t];
                v = fmaxf(v, 0.f);
                lt[(((ks2*8 + strip)*64) + l2b + r)*8 + (lane & 7)] = f2h(v);
            }
        }
    }

    // GEMM2: relu(net) @ W1, acc init = b1
    __syncthreads();
    { const u32x4* g = (const u32x4*)(wp + 32768); u32x4* l = (u32x4*)lw;
      #pragma unroll
      for (int i = 0; i < 8; i++) l[i*256 + tid] = g[i*256 + tid]; }
    __syncthreads();
    f32x4 acc2[2][8];
    #pragma unroll
    for (int s = 0; s < 2; s++)
        #pragma unroll
        for (int t = 0; t < 8; t++){ f32x4 iv = {b1v[t],b1v[t],b1v[t],b1v[t]}; acc2[s][t] = iv; }
    #pragma unroll
    for (int ks = 0; ks < 4; ks++){
        f16x8 a0 = *(const f16x8*)&lt[((ks*8 + w*2 + 0)*64 + lane)*8];
        f16x8 a1 = *(const f16x8*)&lt[((ks*8 + w*2 + 1)*64 + lane)*8];
        #pragma unroll
        for (int t = 0; t < 8; t++){
            f16x8 b = *(const f16x8*)&lw[((ks*8 + t)*64 + lane)*8];
            acc2[0][t] = MFMA16(a0, b, acc2[0][t], 0, 0, 0);
            acc2[1][t] = MFMA16(a1, b, acc2[1][t], 0, 0, 0);
        }
    }

    // GEMM3: shortcut x @ Ws
    for (int c = 0; c < 2; c++){
        __syncthreads();
        { const u32x4* g = (const u32x4*)(wp + 49152 + c*16384); u32x4* l = (u32x4*)lw;
          #pragma unroll
          for (int i = 0; i < 8; i++) l[i*256 + tid] = g[i*256 + tid]; }
        __syncthreads();
        #pragma unroll
        for (int ks = 0; ks < 4; ks++){
            int ko = (c*4 + ks)*32 + quad*8;
            f16x8 a0 = *(const f16x8*)(xb + row0 + ko);
            f16x8 a1 = *(const f16x8*)(xb + row1 + ko);
            #pragma unroll
            for (int t = 0; t < 8; t++){
                f16x8 b = *(const f16x8*)&lw[((ks*8 + t)*64 + lane)*8];
                acc2[0][t] = MFMA16(a0, b, acc2[0][t], 0, 0, 0);
                acc2[1][t] = MFMA16(a1, b, acc2[1][t], 0, 0, 0);
            }
        }
    }

    // epilogue -> xb cols 0..127
    #pragma unroll
    for (int s = 0; s < 2; s++)
        #pragma unroll
        for (int t = 0; t < 8; t++)
            #pragma unroll
            for (int r = 0; r < 4; r++){
                int row = m0 + s*16 + quad*4 + r;
                xb[(size_t)row*256 + t*16 + l15] = f2h(acc2[s][t][r]);
            }
}

// ---- pooling: per-cell segment max, written back to member points' cols 128..255 ----
// one wave per cell (64 lanes x 2 features); mode 0 = store, 1 = accumulate
__global__ __launch_bounds__(256) void k_pool(unsigned short* __restrict__ xb,
        const int* __restrict__ srt, const int* __restrict__ cs, int mode){
    int w = threadIdx.x >> 6, lane = threadIdx.x & 63;
    int c0 = blockIdx.x * 32;
    for (int cc = w; cc < 32; cc += 4){
        int c = c0 + cc;
        int s = cs[c], e = cs[c+1];
        if (s == e) continue;
        float m0 = -1e30f, m1 = -1e30f;
        for (int i = s; i < e; i++){
            int pt = srt[i];
            unsigned v = ((const unsigned*)(xb + (size_t)pt*256))[lane];
            m0 = fmaxf(m0, h2f((unsigned short)(v & 0xFFFF)));
            m1 = fmaxf(m1, h2f((unsigned short)(v >> 16)));
        }
        if (mode){
            for (int i = s; i < e; i++){
                int pt = srt[i];
                unsigned* q = (unsigned*)(xb + (size_t)pt*256 + 128);
                unsigned old = q[lane];
                float a0 = h2f((unsigned short)(old & 0xFFFF)) + m0;
                float a1 = h2f((unsigned short)(old >> 16)) + m1;
                q[lane] = (unsigned)f2h(a0) | ((unsigned)f2h(a1) << 16);
            }
        } else {
            unsigned pk = (unsigned)f2h(m0) | ((unsigned)f2h(m1) << 16);
            for (int i = s; i < e; i++){
                int pt = srt[i];
                ((unsigned*)(xb + (size_t)pt*256 + 128))[lane] = pk;
            }
        }
    }
}

// ---- fc_c via MFMA, c (f16) -> xb cols 128..255 ----
__global__ __launch_bounds__(256) void k_fcc(unsigned short* __restrict__ xb,
        const unsigned short* __restrict__ wcp, const float* __restrict__ bc){
    int tid = threadIdx.x, w = tid >> 6, lane = tid & 63;
    int quad = lane >> 4, l15 = lane & 15;
    int m0 = blockIdx.x*128 + w*32;
    float bv[8];
    #pragma unroll
    for (int t = 0; t < 8; t++) bv[t] = bc[t*16 + l15];
    f32x4 acc[2][8];
    #pragma unroll
    for (int s = 0; s < 2; s++)
        #pragma unroll
        for (int t = 0; t < 8; t++){ f32x4 iv = {bv[t],bv[t],bv[t],bv[t]}; acc[s][t] = iv; }
    const size_t row0 = (size_t)(m0 + l15)*256;
    const size_t row1 = row0 + 16*256;
    #pragma unroll
    for (int ks = 0; ks < 4; ks++){
        int ko = ks*32 + quad*8;
        f16x8 a0 = *(const f16x8*)(xb + row0 + ko);
        f16x8 a1 = *(const f16x8*)(xb + row1 + ko);
        #pragma unroll
        for (int t = 0; t < 8; t++){
            f16x8 b = *(const f16x8*)(wcp + ((ks*8 + t)*64 + lane)*8);
            acc[0][t] = MFMA16(a0, b, acc[0][t], 0, 0, 0);
            acc[1][t] = MFMA16(a1, b, acc[1][t], 0, 0, 0);
        }
    }
    #pragma unroll
    for (int s = 0; s < 2; s++)
        #pragma unroll
        for (int t = 0; t < 8; t++)
            #pragma unroll
            for (int r = 0; r < 4; r++){
                int row = m0 + s*16 + quad*4 + r;
                xb[(size_t)row*256 + 128 + t*16 + l15] = f2h(acc[s][t][r]);
            }
}

// ---- scatter-mean: per-cell segment sum / count, transposed write to out ----
__global__ __launch_bounds__(256) void k_psum(const unsigned short* __restrict__ xb,
        const int* __restrict__ srt, const int* __restrict__ cs,
        float* __restrict__ out, int pl){
    __shared__ float ls[32*129];
    int w = threadIdx.x >> 6, lane = threadIdx.x & 63;
    int c0 = blockIdx.x * 32;
    for (int cc = w; cc < 32; cc += 4){
        int c = c0 + cc;
        int s = cs[c], e = cs[c+1];
        float s0 = 0.f, s1 = 0.f;
        for (int i = s; i < e; i++){
            int pt = srt[i];
            unsigned v = ((const unsigned*)(xb + (size_t)pt*256 + 128))[lane];
            s0 += h2f((unsigned short)(v & 0xFFFF));
            s1 += h2f((unsigned short)(v >> 16));
        }
        float rc = (e > s) ? 1.f/(float)(e - s) : 0.f;
        ls[cc*129 + lane*2]     = s0*rc;
        ls[cc*129 + lane*2 + 1] = s1*rc;
    }
    __syncthreads();
    int pb = pl*2 + (c0 >> 14);
    float* o = out + (size_t)pb*128*R2 + (c0 & 16383);
    #pragma unroll
    for (int j = 0; j < 16; j++){
        int lin = j*256 + threadIdx.x;   // lin = f*32 + cc
        int f = lin >> 5, cc = lin & 31;
        o[(size_t)f*R2 + cc] = ls[cc*129 + f];
    }
}

extern "C" void kernel_launch(void* const* d_in, const int* in_sizes, int n_in,
                              void* d_out, int out_size, void* d_ws, size_t ws_size,
                              hipStream_t stream) {
    const float* p        = (const float*)d_in[0];
    const float* fc_pos_W = (const float*)d_in[1];
    const float* fc_pos_b = (const float*)d_in[2];
    const float* bW0      = (const float*)d_in[3];
    const float* bb0      = (const float*)d_in[4];
    const float* bW1      = (const float*)d_in[5];
    const float* bb1      = (const float*)d_in[6];
    const float* bWs      = (const float*)d_in[7];
    const float* fc_c_W   = (const float*)d_in[8];
    const float* fc_c_b   = (const float*)d_in[9];
    float* out = (float*)d_out;

    char* ws = (char*)d_ws;
    int*            idx   = (int*)ws;                          // 786,432 B
    unsigned short* xbuf  = (unsigned short*)(ws + 786432);    // 33,554,432 B
    int*            srt   = (int*)(ws + 34340864);             // 786,432 B
    int*            cs    = (int*)(ws + 35127296);             // 3*32769*4 -> 393,232 B
    int*            cp    = (int*)(ws + 35520528);             // 393,216 B (hist + running ptr)
    unsigned short* wpack = (unsigned short*)(ws + 35913744);  // 851,968 B

    k_repack<<<1664, 256, 0, stream>>>(bW0, bW1, bWs, fc_c_W, wpack);
    k_idx   <<<TT/256, 256, 0, stream>>>(p, idx);
    k_fcpos <<<TT, 256, 0, stream>>>(p, fc_pos_W, fc_pos_b, xbuf);

    // counting sort by (batch,cell) per plane — idx is round-invariant
    hipMemsetAsync(cp, 0, (size_t)3*32768*4, stream);
    k_hist   <<<TT/256, 256, 0, stream>>>(idx, cp);
    k_scan   <<<3, 1024, 0, stream>>>(cp, cs, cp);   // safe: all reads precede barrier-ordered writes
    // cp now holds exclusive starts again (k_scan rewrote it); use as running ptrs
    k_scatter<<<TT/256, 256, 0, stream>>>(idx, cp, srt);

    k_resnet<<<512, 256, 0, stream>>>(xbuf, wpack, bb0, bb1);
    for (int i = 1; i < 5; i++){
        k_pool<<<1024, 256, 0, stream>>>(xbuf, srt,        cs,          0);
        k_pool<<<1024, 256, 0, stream>>>(xbuf, srt + TT,   cs + 32769, 1);
        k_pool<<<1024, 256, 0, stream>>>(xbuf, srt + 2*TT, cs + 2*32769, 1);
        k_resnet<<<512, 256, 0, stream>>>(xbuf, wpack + (size_t)i*81920,
                                          bb0 + (size_t)i*128, bb1 + (size_t)i*128);
    }

    k_fcc<<<512, 256, 0, stream>>>(xbuf, wpack + 409600, fc_c_b);
    for (int pl = 0; pl < 3; pl++)
        k_psum<<<1024, 256, 0, stream>>>(xbuf, srt + (size_t)pl*TT,
                                         cs + (size_t)pl*32769, out, pl);
}

// Round 4
// 435.331 us; speedup vs baseline: 4.7834x; 1.6644x over previous
//
#include <hip/hip_runtime.h>

#define TT 65536
#define R2 16384

typedef _Float16 f16x8 __attribute__((ext_vector_type(8)));
typedef float    f32x4 __attribute__((ext_vector_type(4)));
typedef unsigned u32x4 __attribute__((ext_vector_type(4)));

#define MFMA16 __builtin_amdgcn_mfma_f32_16x16x32_f16

// ---- helpers ----
__device__ __forceinline__ unsigned short f2h(float f){
    _Float16 h = (_Float16)f;
    return __builtin_bit_cast(unsigned short, h);
}
__device__ __forceinline__ float h2f(unsigned short u){
    return (float)__builtin_bit_cast(_Float16, u);
}
__device__ __forceinline__ unsigned relu2(unsigned w){
    unsigned s = w & 0x80008000u;
    unsigned mask = ((s >> 15) * 0x7FFFu) | s;
    return w & ~mask;
}
__device__ __forceinline__ float nrm(float a){
    float v = a / 1.101f + 0.5f;
    v = fmaxf(v, 0.0f);
    v = fminf(v, 0.99999f);
    return v;
}

// ---- repack weights f32 -> f16 B-fragment layout ----
__global__ __launch_bounds__(256) void k_repack(const float* __restrict__ W0,
        const float* __restrict__ W1, const float* __restrict__ Ws,
        const float* __restrict__ Wc, unsigned short* __restrict__ out){
    int e = blockIdx.x*256 + threadIdx.x;
    const float* src; int r;
    if (e < 409600){
        int i = e / 81920; r = e % 81920;
        if (r < 32768)      { src = W0 + (size_t)i*32768; }
        else if (r < 49152) { src = W1 + (size_t)i*16384; r -= 32768; }
        else                { src = Ws + (size_t)i*32768; r -= 49152; }
    } else { src = Wc; r = e - 409600; }
    int j = r & 7, l = (r >> 3) & 63, t = (r >> 9) & 7, ks = r >> 12;
    int k = ks*32 + (l >> 4)*8 + j;
    int n = t*16 + (l & 15);
    out[e] = f2h(src[k*128 + n]);
}

// ---- indices + histogram (fused) ----
__global__ __launch_bounds__(256) void k_idxhist(const float* __restrict__ p,
        int* __restrict__ idx, int* __restrict__ cnt){
    int pt = blockIdx.x*256 + threadIdx.x;
    float p0 = p[pt*3+0], p1 = p[pt*3+1], p2 = p[pt*3+2];
    int g0 = (int)(nrm(p0)*128.f);
    int g1 = (int)(nrm(p1)*128.f);
    int g2 = (int)(nrm(p2)*128.f);
    int i0 = g0 + 128*g2, i1 = g0 + 128*g1, i2 = g1 + 128*g2;
    idx[0*TT + pt] = i0;
    idx[1*TT + pt] = i1;
    idx[2*TT + pt] = i2;
    int b14 = (pt >> 15) << 14;
    atomicAdd(&cnt[0*32768 + b14 + i0], 1);
    atomicAdd(&cnt[1*32768 + b14 + i1], 1);
    atomicAdd(&cnt[2*32768 + b14 + i2], 1);
}

// ---- exclusive scan (1 block of 1024 per plane); cnt may alias cp ----
__global__ __launch_bounds__(1024) void k_scan(const int* __restrict__ cnt,
        int* __restrict__ cs, int* __restrict__ cp){
    __shared__ int ls[1024];
    int pl = blockIdx.x, tid = threadIdx.x;
    const int* c = cnt + pl*32768;
    int v[32], tot = 0;
    #pragma unroll
    for (int j = 0; j < 32; j++){ v[j] = c[tid*32 + j]; tot += v[j]; }
    int x = tot;
    ls[tid] = x; __syncthreads();
    for (int off = 1; off < 1024; off <<= 1){
        int add = (tid >= off) ? ls[tid - off] : 0;
        __syncthreads();
        x += add; ls[tid] = x;
        __syncthreads();
    }
    int run = x - tot;
    #pragma unroll
    for (int j = 0; j < 32; j++){
        cs[pl*32769 + tid*32 + j] = run;
        cp[pl*32768 + tid*32 + j] = run;
        run += v[j];
    }
    if (tid == 1023) cs[pl*32769 + 32768] = TT;
}

// ---- counting sort: scatter point ids ----
__global__ __launch_bounds__(256) void k_scatter(const int* __restrict__ idx,
        int* __restrict__ cp, int* __restrict__ srt){
    int pt = blockIdx.x*256 + threadIdx.x;
    int b14 = (pt >> 15) << 14;
    #pragma unroll
    for (int pl = 0; pl < 3; pl++){
        int pos = atomicAdd(&cp[pl*32768 + b14 + idx[pl*TT + pt]], 1);
        srt[pl*TT + pos] = pt;
    }
}

// ---- fc_pos ----
__global__ __launch_bounds__(256) void k_fcpos(const float* __restrict__ p,
        const float* __restrict__ W, const float* __restrict__ b,
        unsigned short* __restrict__ xb){
    int pt = blockIdx.x;
    int j  = threadIdx.x;
    float p0 = p[pt*3+0], p1 = p[pt*3+1], p2 = p[pt*3+2];
    float v = b[j] + p0*W[j] + p1*W[256+j] + p2*W[512+j];
    xb[(size_t)pt*256 + j] = f2h(v);
}

// ---- per-cell max -> compact plane buffer mxp[pl][b*R2+cell][128] (f16) ----
__global__ __launch_bounds__(256) void k_pool3(const unsigned short* __restrict__ xb,
        const int* __restrict__ srt, const int* __restrict__ cs,
        unsigned short* __restrict__ mxp){
    int pl = blockIdx.y;
    const int* srtp = srt + (size_t)pl*TT;
    const int* csp  = cs  + (size_t)pl*32769;
    int lane = threadIdx.x & 63;
    int c = blockIdx.x*4 + (threadIdx.x >> 6);
    int s = csp[c], e = csp[c+1];
    if (s == e) return;
    float m0 = -1e30f, m1 = -1e30f;
    int pt = srtp[s];
    for (int i = s; i < e; i++){
        int ptn = (i+1 < e) ? srtp[i+1] : 0;
        unsigned v = ((const unsigned*)(xb + (size_t)pt*256))[lane];
        m0 = fmaxf(m0, h2f((unsigned short)(v & 0xFFFF)));
        m1 = fmaxf(m1, h2f((unsigned short)(v >> 16)));
        pt = ptn;
    }
    unsigned pk = (unsigned)f2h(m0) | ((unsigned)f2h(m1) << 16);
    ((unsigned*)(mxp + ((size_t)pl*32768 + c)*128))[lane] = pk;
}

// ---- fused ResnetBlockFC via MFMA; pooled half gathered from mxp in-register ----
__global__ __launch_bounds__(256) void k_resnet(unsigned short* __restrict__ xb,
        const unsigned short* __restrict__ wp,
        const float* __restrict__ b0, const float* __restrict__ b1,
        const int* __restrict__ idx, const unsigned short* __restrict__ mxp){
    __shared__ __align__(16) unsigned short lds[32768];
    unsigned short* lw = lds;
    unsigned short* lt = lds + 16384;
    int tid = threadIdx.x, w = tid >> 6, lane = tid & 63;
    int quad = lane >> 4, l15 = lane & 15;
    int m0 = blockIdx.x*128 + w*32;
    float b0v[8], b1v[8];
    #pragma unroll
    for (int t = 0; t < 8; t++){ b0v[t] = b0[t*16 + l15]; b1v[t] = b1[t*16 + l15]; }

    // ---- preload A fragments: xf = raw x cols 0..127; pf = pooled cols 128..255 ----
    u32x4 xf[2][4]; f16x8 pf[2][4];
    #pragma unroll
    for (int s = 0; s < 2; s++){
        size_t rb = (size_t)(m0 + s*16 + l15)*256;
        #pragma unroll
        for (int ks = 0; ks < 4; ks++)
            xf[s][ks] = *(const u32x4*)(xb + rb + ks*32 + quad*8);
    }
    if (mxp){
        #pragma unroll
        for (int s = 0; s < 2; s++){
            int row = m0 + s*16 + l15;
            int b14 = (row >> 15) << 14;
            const unsigned short* q0 = mxp + ((size_t)(0*32768 + b14 + idx[row]))*128;
            const unsigned short* q1 = mxp + ((size_t)(1*32768 + b14 + idx[TT + row]))*128;
            const unsigned short* q2 = mxp + ((size_t)(2*32768 + b14 + idx[2*TT + row]))*128;
            #pragma unroll
            for (int ks = 0; ks < 4; ks++){
                int col = ks*32 + quad*8;
                f16x8 a = *(const f16x8*)(q0 + col);
                f16x8 b = *(const f16x8*)(q1 + col);
                f16x8 c = *(const f16x8*)(q2 + col);
                f16x8 r;
                #pragma unroll
                for (int j = 0; j < 8; j++)
                    r[j] = (_Float16)((float)a[j] + (float)b[j] + (float)c[j]);
                pf[s][ks] = r;
            }
        }
    } else {
        #pragma unroll
        for (int s = 0; s < 2; s++){
            size_t rb = (size_t)(m0 + s*16 + l15)*256 + 128;
            #pragma unroll
            for (int ks = 0; ks < 4; ks++)
                pf[s][ks] = *(const f16x8*)(xb + rb + ks*32 + quad*8);
        }
    }

    f32x4 acc[2][8];
    #pragma unroll
    for (int s = 0; s < 2; s++)
        #pragma unroll
        for (int t = 0; t < 8; t++){ f32x4 z = {0.f,0.f,0.f,0.f}; acc[s][t] = z; }

    // ---- GEMM1: relu(x) @ W0 ----
    #pragma unroll
    for (int c = 0; c < 2; c++){
        __syncthreads();
        { const u32x4* g = (const u32x4*)(wp + c*16384); u32x4* l = (u32x4*)lw;
          #pragma unroll
          for (int i = 0; i < 8; i++) l[i*256 + tid] = g[i*256 + tid]; }
        __syncthreads();
        #pragma unroll
        for (int ks = 0; ks < 4; ks++){
            u32x4 u0 = (c == 0) ? xf[0][ks] : __builtin_bit_cast(u32x4, pf[0][ks]);
            u32x4 u1 = (c == 0) ? xf[1][ks] : __builtin_bit_cast(u32x4, pf[1][ks]);
            u0.x = relu2(u0.x); u0.y = relu2(u0.y); u0.z = relu2(u0.z); u0.w = relu2(u0.w);
            u1.x = relu2(u1.x); u1.y = relu2(u1.y); u1.z = relu2(u1.z); u1.w = relu2(u1.w);
            f16x8 a0 = __builtin_bit_cast(f16x8, u0);
            f16x8 a1 = __builtin_bit_cast(f16x8, u1);
            #pragma unroll
            for (int t = 0; t < 8; t++){
                f16x8 b = *(const f16x8*)&lw[((ks*8 + t)*64 + lane)*8];
                acc[0][t] = MFMA16(a0, b, acc[0][t], 0, 0, 0);
                acc[1][t] = MFMA16(a1, b, acc[1][t], 0, 0, 0);
            }
        }
    }

    // ---- transform relu(net+b0) -> A-fragment layout in lt ----
    #pragma unroll
    for (int s = 0; s < 2; s++){
        int strip = w*2 + s;
        #pragma unroll
        for (int t = 0; t < 8; t++){
            int ks2 = t >> 1;
            int l2b = ((t & 1)*2 + ((lane >> 3) & 1))*16 + quad*4;
            #pragma unroll
            for (int r = 0; r < 4; r++){
                float v = acc[s][t][r] + b0v[t];
                v = fmaxf(v, 0.f);
                lt[(((ks2*8 + strip)*64) + l2b + r)*8 + (lane & 7)] = f2h(v);
            }
        }
    }

    // ---- GEMM2: relu(net) @ W1, acc init = b1 ----
    __syncthreads();
    { const u32x4* g = (const u32x4*)(wp + 32768); u32x4* l = (u32x4*)lw;
      #pragma unroll
      for (int i = 0; i < 8; i++) l[i*256 + tid] = g[i*256 + tid]; }
    __syncthreads();
    f32x4 acc2[2][8];
    #pragma unroll
    for (int s = 0; s < 2; s++)
        #pragma unroll
        for (int t = 0; t < 8; t++){ f32x4 iv = {b1v[t],b1v[t],b1v[t],b1v[t]}; acc2[s][t] = iv; }
    #pragma unroll
    for (int ks = 0; ks < 4; ks++){
        f16x8 a0 = *(const f16x8*)&lt[((ks*8 + w*2 + 0)*64 + lane)*8];
        f16x8 a1 = *(const f16x8*)&lt[((ks*8 + w*2 + 1)*64 + lane)*8];
        #pragma unroll
        for (int t = 0; t < 8; t++){
            f16x8 b = *(const f16x8*)&lw[((ks*8 + t)*64 + lane)*8];
            acc2[0][t] = MFMA16(a0, b, acc2[0][t], 0, 0, 0);
            acc2[1][t] = MFMA16(a1, b, acc2[1][t], 0, 0, 0);
        }
    }

    // ---- GEMM3: shortcut x @ Ws ----
    #pragma unroll
    for (int c = 0; c < 2; c++){
        __syncthreads();
        { const u32x4* g = (const u32x4*)(wp + 49152 + c*16384); u32x4* l = (u32x4*)lw;
          #pragma unroll
          for (int i = 0; i < 8; i++) l[i*256 + tid] = g[i*256 + tid]; }
        __syncthreads();
        #pragma unroll
        for (int ks = 0; ks < 4; ks++){
            f16x8 a0 = (c == 0) ? __builtin_bit_cast(f16x8, xf[0][ks]) : pf[0][ks];
            f16x8 a1 = (c == 0) ? __builtin_bit_cast(f16x8, xf[1][ks]) : pf[1][ks];
            #pragma unroll
            for (int t = 0; t < 8; t++){
                f16x8 b = *(const f16x8*)&lw[((ks*8 + t)*64 + lane)*8];
                acc2[0][t] = MFMA16(a0, b, acc2[0][t], 0, 0, 0);
                acc2[1][t] = MFMA16(a1, b, acc2[1][t], 0, 0, 0);
            }
        }
    }

    // ---- epilogue -> xb cols 0..127 ----
    #pragma unroll
    for (int s = 0; s < 2; s++)
        #pragma unroll
        for (int t = 0; t < 8; t++)
            #pragma unroll
            for (int r = 0; r < 4; r++){
                int row = m0 + s*16 + quad*4 + r;
                xb[(size_t)row*256 + t*16 + l15] = f2h(acc2[s][t][r]);
            }
}

// ---- fc_c via MFMA, c (f16) -> xb cols 128..255 ----
__global__ __launch_bounds__(256) void k_fcc(unsigned short* __restrict__ xb,
        const unsigned short* __restrict__ wcp, const float* __restrict__ bc){
    int tid = threadIdx.x, w = tid >> 6, lane = tid & 63;
    int quad = lane >> 4, l15 = lane & 15;
    int m0 = blockIdx.x*128 + w*32;
    float bv[8];
    #pragma unroll
    for (int t = 0; t < 8; t++) bv[t] = bc[t*16 + l15];
    f32x4 acc[2][8];
    #pragma unroll
    for (int s = 0; s < 2; s++)
        #pragma unroll
        for (int t = 0; t < 8; t++){ f32x4 iv = {bv[t],bv[t],bv[t],bv[t]}; acc[s][t] = iv; }
    const size_t row0 = (size_t)(m0 + l15)*256;
    const size_t row1 = row0 + 16*256;
    #pragma unroll
    for (int ks = 0; ks < 4; ks++){
        int ko = ks*32 + quad*8;
        f16x8 a0 = *(const f16x8*)(xb + row0 + ko);
        f16x8 a1 = *(const f16x8*)(xb + row1 + ko);
        #pragma unroll
        for (int t = 0; t < 8; t++){
            f16x8 b = *(const f16x8*)(wcp + ((ks*8 + t)*64 + lane)*8);
            acc[0][t] = MFMA16(a0, b, acc[0][t], 0, 0, 0);
            acc[1][t] = MFMA16(a1, b, acc[1][t], 0, 0, 0);
        }
    }
    #pragma unroll
    for (int s = 0; s < 2; s++)
        #pragma unroll
        for (int t = 0; t < 8; t++)
            #pragma unroll
            for (int r = 0; r < 4; r++){
                int row = m0 + s*16 + quad*4 + r;
                xb[(size_t)row*256 + 128 + t*16 + l15] = f2h(acc[s][t][r]);
            }
}

// ---- scatter-mean + transpose, all planes in one launch ----
__global__ __launch_bounds__(1024) void k_psum3(const unsigned short* __restrict__ xb,
        const int* __restrict__ srt, const int* __restrict__ cs,
        float* __restrict__ out){
    __shared__ float ls[32*129];
    int pl = blockIdx.y;
    const int* srtp = srt + (size_t)pl*TT;
    const int* csp  = cs  + (size_t)pl*32769;
    int w = threadIdx.x >> 6, lane = threadIdx.x & 63;
    int c0 = blockIdx.x * 32;
    #pragma unroll
    for (int cc = w; cc < 32; cc += 16){
        int c = c0 + cc;
        int s = csp[c], e = csp[c+1];
        float s0 = 0.f, s1 = 0.f;
        if (s < e){
            int pt = srtp[s];
            for (int i = s; i < e; i++){
                int ptn = (i+1 < e) ? srtp[i+1] : 0;
                unsigned v = ((const unsigned*)(xb + (size_t)pt*256 + 128))[lane];
                s0 += h2f((unsigned short)(v & 0xFFFF));
                s1 += h2f((unsigned short)(v >> 16));
                pt = ptn;
            }
        }
        float rc = (e > s) ? 1.f/(float)(e - s) : 0.f;
        ls[cc*129 + lane*2]     = s0*rc;
        ls[cc*129 + lane*2 + 1] = s1*rc;
    }
    __syncthreads();
    int pb = pl*2 + (c0 >> 14);
    float* o = out + (size_t)pb*128*R2 + (c0 & 16383);
    #pragma unroll
    for (int j = 0; j < 4; j++){
        int lin = j*1024 + threadIdx.x;   // lin = f*32 + cc
        int f = lin >> 5, cc = lin & 31;
        o[(size_t)f*R2 + cc] = ls[cc*129 + f];
    }
}

extern "C" void kernel_launch(void* const* d_in, const int* in_sizes, int n_in,
                              void* d_out, int out_size, void* d_ws, size_t ws_size,
                              hipStream_t stream) {
    const float* p        = (const float*)d_in[0];
    const float* fc_pos_W = (const float*)d_in[1];
    const float* fc_pos_b = (const float*)d_in[2];
    const float* bW0      = (const float*)d_in[3];
    const float* bb0      = (const float*)d_in[4];
    const float* bW1      = (const float*)d_in[5];
    const float* bb1      = (const float*)d_in[6];
    const float* bWs      = (const float*)d_in[7];
    const float* fc_c_W   = (const float*)d_in[8];
    const float* fc_c_b   = (const float*)d_in[9];
    float* out = (float*)d_out;

    char* ws = (char*)d_ws;
    int*            idx   = (int*)ws;                          // 786,432 B
    unsigned short* xbuf  = (unsigned short*)(ws + 786432);    // 33,554,432 B
    int*            srt   = (int*)(ws + 34340864);             // 786,432 B
    int*            cs    = (int*)(ws + 35127296);             // 393,232 B
    int*            cp    = (int*)(ws + 35520528);             // 393,216 B
    unsigned short* wpack = (unsigned short*)(ws + 35913744);  // 851,968 B
    unsigned short* mxp   = (unsigned short*)(ws + 36765712);  // 25,165,824 B

    k_repack<<<1664, 256, 0, stream>>>(bW0, bW1, bWs, fc_c_W, wpack);
    hipMemsetAsync(cp, 0, (size_t)3*32768*4, stream);
    k_idxhist<<<TT/256, 256, 0, stream>>>(p, idx, cp);
    k_scan   <<<3, 1024, 0, stream>>>(cp, cs, cp);
    k_scatter<<<TT/256, 256, 0, stream>>>(idx, cp, srt);
    k_fcpos  <<<TT, 256, 0, stream>>>(p, fc_pos_W, fc_pos_b, xbuf);

    k_resnet<<<512, 256, 0, stream>>>(xbuf, wpack, bb0, bb1, idx, (const unsigned short*)nullptr);
    for (int i = 1; i < 5; i++){
        k_pool3<<<dim3(8192, 3), 256, 0, stream>>>(xbuf, srt, cs, mxp);
        k_resnet<<<512, 256, 0, stream>>>(xbuf, wpack + (size_t)i*81920,
                                          bb0 + (size_t)i*128, bb1 + (size_t)i*128,
                                          idx, mxp);
    }

    k_fcc  <<<512, 256, 0, stream>>>(xbuf, wpack + 409600, fc_c_b);
    k_psum3<<<dim3(1024, 3), 1024, 0, stream>>>(xbuf, srt, cs, out);
}

// Round 5
// 412.754 us; speedup vs baseline: 5.0450x; 1.0547x over previous
//
#include <hip/hip_runtime.h>

#define TT 65536
#define R2 16384

typedef _Float16 f16x8 __attribute__((ext_vector_type(8)));
typedef float    f32x4 __attribute__((ext_vector_type(4)));
typedef unsigned u32x4 __attribute__((ext_vector_type(4)));

#define MFMA16 __builtin_amdgcn_mfma_f32_16x16x32_f16

// ---- helpers ----
__device__ __forceinline__ unsigned short f2h(float f){
    _Float16 h = (_Float16)f;
    return __builtin_bit_cast(unsigned short, h);
}
__device__ __forceinline__ float h2f(unsigned short u){
    return (float)__builtin_bit_cast(_Float16, u);
}
__device__ __forceinline__ unsigned relu2(unsigned w){
    unsigned s = w & 0x80008000u;
    unsigned mask = ((s >> 15) * 0x7FFFu) | s;
    return w & ~mask;
}
__device__ __forceinline__ float nrm(float a){
    float v = a / 1.101f + 0.5f;
    v = fmaxf(v, 0.0f);
    v = fminf(v, 0.99999f);
    return v;
}

// ---- repack weights f32 -> f16 B-fragment layout ----
__global__ __launch_bounds__(256) void k_repack(const float* __restrict__ W0,
        const float* __restrict__ W1, const float* __restrict__ Ws,
        const float* __restrict__ Wc, unsigned short* __restrict__ out){
    int e = blockIdx.x*256 + threadIdx.x;
    const float* src; int r;
    if (e < 409600){
        int i = e / 81920; r = e % 81920;
        if (r < 32768)      { src = W0 + (size_t)i*32768; }
        else if (r < 49152) { src = W1 + (size_t)i*16384; r -= 32768; }
        else                { src = Ws + (size_t)i*32768; r -= 49152; }
    } else { src = Wc; r = e - 409600; }
    int j = r & 7, l = (r >> 3) & 63, t = (r >> 9) & 7, ks = r >> 12;
    int k = ks*32 + (l >> 4)*8 + j;
    int n = t*16 + (l & 15);
    out[e] = f2h(src[k*128 + n]);
}

// ---- indices + histogram (fused) ----
__global__ __launch_bounds__(256) void k_idxhist(const float* __restrict__ p,
        int* __restrict__ idx, int* __restrict__ cnt){
    int pt = blockIdx.x*256 + threadIdx.x;
    float p0 = p[pt*3+0], p1 = p[pt*3+1], p2 = p[pt*3+2];
    int g0 = (int)(nrm(p0)*128.f);
    int g1 = (int)(nrm(p1)*128.f);
    int g2 = (int)(nrm(p2)*128.f);
    int i0 = g0 + 128*g2, i1 = g0 + 128*g1, i2 = g1 + 128*g2;
    idx[0*TT + pt] = i0;
    idx[1*TT + pt] = i1;
    idx[2*TT + pt] = i2;
    int b14 = (pt >> 15) << 14;
    atomicAdd(&cnt[0*32768 + b14 + i0], 1);
    atomicAdd(&cnt[1*32768 + b14 + i1], 1);
    atomicAdd(&cnt[2*32768 + b14 + i2], 1);
}

// ---- exclusive scan (1 block of 1024 per plane); cnt may alias cp ----
__global__ __launch_bounds__(1024) void k_scan(const int* __restrict__ cnt,
        int* __restrict__ cs, int* __restrict__ cp){
    __shared__ int ls[1024];
    int pl = blockIdx.x, tid = threadIdx.x;
    const int* c = cnt + pl*32768;
    int v[32], tot = 0;
    #pragma unroll
    for (int j = 0; j < 32; j++){ v[j] = c[tid*32 + j]; tot += v[j]; }
    int x = tot;
    ls[tid] = x; __syncthreads();
    for (int off = 1; off < 1024; off <<= 1){
        int add = (tid >= off) ? ls[tid - off] : 0;
        __syncthreads();
        x += add; ls[tid] = x;
        __syncthreads();
    }
    int run = x - tot;
    #pragma unroll
    for (int j = 0; j < 32; j++){
        cs[pl*32769 + tid*32 + j] = run;
        cp[pl*32768 + tid*32 + j] = run;
        run += v[j];
    }
    if (tid == 1023) cs[pl*32769 + 32768] = TT;
}

// ---- counting sort: scatter point ids ----
__global__ __launch_bounds__(256) void k_scatter(const int* __restrict__ idx,
        int* __restrict__ cp, int* __restrict__ srt){
    int pt = blockIdx.x*256 + threadIdx.x;
    int b14 = (pt >> 15) << 14;
    #pragma unroll
    for (int pl = 0; pl < 3; pl++){
        int pos = atomicAdd(&cp[pl*32768 + b14 + idx[pl*TT + pt]], 1);
        srt[pl*TT + pos] = pt;
    }
}

// ---- per-cell max -> compact plane buffer mxp[pl][b*R2+cell][128] (f16) ----
__global__ __launch_bounds__(256) void k_pool3(const unsigned short* __restrict__ xb,
        const int* __restrict__ srt, const int* __restrict__ cs,
        unsigned short* __restrict__ mxp){
    int pl = blockIdx.y;
    const int* srtp = srt + (size_t)pl*TT;
    const int* csp  = cs  + (size_t)pl*32769;
    int lane = threadIdx.x & 63;
    int c = blockIdx.x*4 + (threadIdx.x >> 6);
    int s = csp[c], e = csp[c+1];
    if (s == e) return;
    float m0 = -1e30f, m1 = -1e30f;
    int pt = srtp[s];
    for (int i = s; i < e; i++){
        int ptn = (i+1 < e) ? srtp[i+1] : 0;
        unsigned v = ((const unsigned*)(xb + (size_t)pt*256))[lane];
        m0 = fmaxf(m0, h2f((unsigned short)(v & 0xFFFF)));
        m1 = fmaxf(m1, h2f((unsigned short)(v >> 16)));
        pt = ptn;
    }
    unsigned pk = (unsigned)f2h(m0) | ((unsigned)f2h(m1) << 16);
    ((unsigned*)(mxp + ((size_t)pl*32768 + c)*128))[lane] = pk;
}

// ---- fused ResnetBlockFC (+optional fc_pos head, +optional fc_c tail) ----
// pin != null : compute x fragments from p (first block); else read xb + gather mxp
// wc  != null : fuse fc_c, write c to xb cols 128..255 and skip net write
__global__ __launch_bounds__(256, 2) void k_resnet(unsigned short* __restrict__ xb,
        const unsigned short* __restrict__ wp,
        const float* __restrict__ b0, const float* __restrict__ b1,
        const int* __restrict__ idx, const unsigned short* __restrict__ mxp,
        const float* __restrict__ pin, const float* __restrict__ fW,
        const float* __restrict__ fb,
        const unsigned short* __restrict__ wc, const float* __restrict__ bc){
    __shared__ __align__(16) unsigned short lds[32768];
    unsigned short* lw = lds;
    unsigned short* lt = lds + 16384;
    int tid = threadIdx.x, w = tid >> 6, lane = tid & 63;
    int quad = lane >> 4, l15 = lane & 15;
    int m0 = blockIdx.x*128 + w*32;
    float b0v[8], b1v[8];
    #pragma unroll
    for (int t = 0; t < 8; t++){ b0v[t] = b0[t*16 + l15]; b1v[t] = b1[t*16 + l15]; }

    u32x4 pre[8];
    auto preload = [&](const unsigned short* src){
        const u32x4* g = (const u32x4*)src;
        #pragma unroll
        for (int i = 0; i < 8; i++) pre[i] = g[i*256 + tid];
    };
    auto flush = [&](){
        u32x4* l = (u32x4*)lw;
        #pragma unroll
        for (int i = 0; i < 8; i++) l[i*256 + tid] = pre[i];
    };

    preload(wp);   // phase 0 weights in flight during A-fragment setup

    // ---- A fragments: xf = x cols 0..127, pf = cols 128..255 ----
    u32x4 xf[2][4]; f16x8 pf[2][4];
    if (pin){
        #pragma unroll
        for (int s = 0; s < 2; s++){
            int row = m0 + s*16 + l15;
            float p0 = pin[row*3+0], p1 = pin[row*3+1], p2 = pin[row*3+2];
            #pragma unroll
            for (int ks = 0; ks < 4; ks++){
                int c0 = ks*32 + quad*8;
                unsigned short hx[8], hp[8];
                #pragma unroll
                for (int h = 0; h < 2; h++){
                    f32x4 w0 = *(const f32x4*)(fW + c0 + h*4);
                    f32x4 w1 = *(const f32x4*)(fW + 256 + c0 + h*4);
                    f32x4 w2 = *(const f32x4*)(fW + 512 + c0 + h*4);
                    f32x4 bb = *(const f32x4*)(fb + c0 + h*4);
                    f32x4 v0 = *(const f32x4*)(fW + 128 + c0 + h*4);
                    f32x4 v1 = *(const f32x4*)(fW + 384 + c0 + h*4);
                    f32x4 v2 = *(const f32x4*)(fW + 640 + c0 + h*4);
                    f32x4 bp = *(const f32x4*)(fb + 128 + c0 + h*4);
                    #pragma unroll
                    for (int j = 0; j < 4; j++){
                        hx[h*4+j] = f2h(bb[j] + p0*w0[j] + p1*w1[j] + p2*w2[j]);
                        hp[h*4+j] = f2h(bp[j] + p0*v0[j] + p1*v1[j] + p2*v2[j]);
                    }
                }
                unsigned short* dx = (unsigned short*)&xf[s][ks];
                unsigned short* dp = (unsigned short*)&pf[s][ks];
                #pragma unroll
                for (int j = 0; j < 8; j++){ dx[j] = hx[j]; dp[j] = hp[j]; }
            }
        }
    } else {
        #pragma unroll
        for (int s = 0; s < 2; s++){
            size_t rb = (size_t)(m0 + s*16 + l15)*256;
            #pragma unroll
            for (int ks = 0; ks < 4; ks++)
                xf[s][ks] = *(const u32x4*)(xb + rb + ks*32 + quad*8);
        }
        #pragma unroll
        for (int s = 0; s < 2; s++){
            int row = m0 + s*16 + l15;
            int b14 = (row >> 15) << 14;
            const unsigned short* q0 = mxp + ((size_t)(0*32768 + b14 + idx[row]))*128;
            const unsigned short* q1 = mxp + ((size_t)(1*32768 + b14 + idx[TT + row]))*128;
            const unsigned short* q2 = mxp + ((size_t)(2*32768 + b14 + idx[2*TT + row]))*128;
            #pragma unroll
            for (int ks = 0; ks < 4; ks++){
                int col = ks*32 + quad*8;
                f16x8 a = *(const f16x8*)(q0 + col);
                f16x8 b = *(const f16x8*)(q1 + col);
                f16x8 c = *(const f16x8*)(q2 + col);
                f16x8 r;
                #pragma unroll
                for (int j = 0; j < 8; j++)
                    r[j] = (_Float16)((float)a[j] + (float)b[j] + (float)c[j]);
                pf[s][ks] = r;
            }
        }
    }

    f32x4 acc[2][8];
    #pragma unroll
    for (int s = 0; s < 2; s++)
        #pragma unroll
        for (int t = 0; t < 8; t++){ f32x4 z = {0.f,0.f,0.f,0.f}; acc[s][t] = z; }

    // ---- phase 0: GEMM1 chunk 0 (relu(xf) @ W0a) ----
    __syncthreads(); flush(); __syncthreads();
    preload(wp + 16384);
    {
        #pragma unroll
        for (int ks = 0; ks < 4; ks++){
            u32x4 u0 = xf[0][ks], u1 = xf[1][ks];
            u0.x = relu2(u0.x); u0.y = relu2(u0.y); u0.z = relu2(u0.z); u0.w = relu2(u0.w);
            u1.x = relu2(u1.x); u1.y = relu2(u1.y); u1.z = relu2(u1.z); u1.w = relu2(u1.w);
            f16x8 a0 = __builtin_bit_cast(f16x8, u0);
            f16x8 a1 = __builtin_bit_cast(f16x8, u1);
            #pragma unroll
            for (int t = 0; t < 8; t++){
                f16x8 b = *(const f16x8*)&lw[((ks*8 + t)*64 + lane)*8];
                acc[0][t] = MFMA16(a0, b, acc[0][t], 0, 0, 0);
                acc[1][t] = MFMA16(a1, b, acc[1][t], 0, 0, 0);
            }
        }
    }

    // ---- phase 1: GEMM1 chunk 1 (relu(pf) @ W0b) ----
    __syncthreads(); flush(); __syncthreads();
    preload(wp + 32768);
    {
        #pragma unroll
        for (int ks = 0; ks < 4; ks++){
            u32x4 u0 = __builtin_bit_cast(u32x4, pf[0][ks]);
            u32x4 u1 = __builtin_bit_cast(u32x4, pf[1][ks]);
            u0.x = relu2(u0.x); u0.y = relu2(u0.y); u0.z = relu2(u0.z); u0.w = relu2(u0.w);
            u1.x = relu2(u1.x); u1.y = relu2(u1.y); u1.z = relu2(u1.z); u1.w = relu2(u1.w);
            f16x8 a0 = __builtin_bit_cast(f16x8, u0);
            f16x8 a1 = __builtin_bit_cast(f16x8, u1);
            #pragma unroll
            for (int t = 0; t < 8; t++){
                f16x8 b = *(const f16x8*)&lw[((ks*8 + t)*64 + lane)*8];
                acc[0][t] = MFMA16(a0, b, acc[0][t], 0, 0, 0);
                acc[1][t] = MFMA16(a1, b, acc[1][t], 0, 0, 0);
            }
        }
    }

    // ---- phase 2: transform relu(net+b0) -> lt, GEMM2 (lt @ W1), acc2 init b1 ----
    __syncthreads(); flush(); __syncthreads();
    preload(wp + 49152);
    f32x4 acc2[2][8];
    #pragma unroll
    for (int s = 0; s < 2; s++){
        int strip = w*2 + s;
        #pragma unroll
        for (int t = 0; t < 8; t++){
            int ks2 = t >> 1;
            int l2b = ((t & 1)*2 + ((lane >> 3) & 1))*16 + quad*4;
            #pragma unroll
            for (int r = 0; r < 4; r++){
                float v = acc[s][t][r] + b0v[t];
                v = fmaxf(v, 0.f);
                lt[(((ks2*8 + strip)*64) + l2b + r)*8 + (lane & 7)] = f2h(v);
            }
        }
    }
    #pragma unroll
    for (int s = 0; s < 2; s++)
        #pragma unroll
        for (int t = 0; t < 8; t++){ f32x4 iv = {b1v[t],b1v[t],b1v[t],b1v[t]}; acc2[s][t] = iv; }
    #pragma unroll
    for (int ks = 0; ks < 4; ks++){
        f16x8 a0 = *(const f16x8*)&lt[((ks*8 + w*2 + 0)*64 + lane)*8];
        f16x8 a1 = *(const f16x8*)&lt[((ks*8 + w*2 + 1)*64 + lane)*8];
        #pragma unroll
        for (int t = 0; t < 8; t++){
            f16x8 b = *(const f16x8*)&lw[((ks*8 + t)*64 + lane)*8];
            acc2[0][t] = MFMA16(a0, b, acc2[0][t], 0, 0, 0);
            acc2[1][t] = MFMA16(a1, b, acc2[1][t], 0, 0, 0);
        }
    }

    // ---- phase 3: GEMM3 chunk 0 (xf @ Wsa) ----
    __syncthreads(); flush(); __syncthreads();
    preload(wp + 65536);
    {
        #pragma unroll
        for (int ks = 0; ks < 4; ks++){
            f16x8 a0 = __builtin_bit_cast(f16x8, xf[0][ks]);
            f16x8 a1 = __builtin_bit_cast(f16x8, xf[1][ks]);
            #pragma unroll
            for (int t = 0; t < 8; t++){
                f16x8 b = *(const f16x8*)&lw[((ks*8 + t)*64 + lane)*8];
                acc2[0][t] = MFMA16(a0, b, acc2[0][t], 0, 0, 0);
                acc2[1][t] = MFMA16(a1, b, acc2[1][t], 0, 0, 0);
            }
        }
    }

    // ---- phase 4: GEMM3 chunk 1 (pf @ Wsb) ----
    __syncthreads(); flush(); __syncthreads();
    if (wc) preload(wc);
    {
        #pragma unroll
        for (int ks = 0; ks < 4; ks++){
            f16x8 a0 = pf[0][ks];
            f16x8 a1 = pf[1][ks];
            #pragma unroll
            for (int t = 0; t < 8; t++){
                f16x8 b = *(const f16x8*)&lw[((ks*8 + t)*64 + lane)*8];
                acc2[0][t] = MFMA16(a0, b, acc2[0][t], 0, 0, 0);
                acc2[1][t] = MFMA16(a1, b, acc2[1][t], 0, 0, 0);
            }
        }
    }

    if (!wc){
        // ---- epilogue: net -> xb cols 0..127 ----
        #pragma unroll
        for (int s = 0; s < 2; s++)
            #pragma unroll
            for (int t = 0; t < 8; t++)
                #pragma unroll
                for (int r = 0; r < 4; r++){
                    int row = m0 + s*16 + quad*4 + r;
                    xb[(size_t)row*256 + t*16 + l15] = f2h(acc2[s][t][r]);
                }
        return;
    }

    // ---- phase 5 (fused fc_c): transform net -> lt (no relu), GEMM (lt @ Wc) ----
    __syncthreads(); flush(); __syncthreads();
    #pragma unroll
    for (int s = 0; s < 2; s++){
        int strip = w*2 + s;
        #pragma unroll
        for (int t = 0; t < 8; t++){
            int ks2 = t >> 1;
            int l2b = ((t & 1)*2 + ((lane >> 3) & 1))*16 + quad*4;
            #pragma unroll
            for (int r = 0; r < 4; r++)
                lt[(((ks2*8 + strip)*64) + l2b + r)*8 + (lane & 7)] = f2h(acc2[s][t][r]);
        }
    }
    f32x4 acc3[2][8];
    #pragma unroll
    for (int t = 0; t < 8; t++){
        float bv = bc[t*16 + l15];
        f32x4 iv = {bv, bv, bv, bv};
        acc3[0][t] = iv; acc3[1][t] = iv;
    }
    #pragma unroll
    for (int ks = 0; ks < 4; ks++){
        f16x8 a0 = *(const f16x8*)&lt[((ks*8 + w*2 + 0)*64 + lane)*8];
        f16x8 a1 = *(const f16x8*)&lt[((ks*8 + w*2 + 1)*64 + lane)*8];
        #pragma unroll
        for (int t = 0; t < 8; t++){
            f16x8 b = *(const f16x8*)&lw[((ks*8 + t)*64 + lane)*8];
            acc3[0][t] = MFMA16(a0, b, acc3[0][t], 0, 0, 0);
            acc3[1][t] = MFMA16(a1, b, acc3[1][t], 0, 0, 0);
        }
    }
    #pragma unroll
    for (int s = 0; s < 2; s++)
        #pragma unroll
        for (int t = 0; t < 8; t++)
            #pragma unroll
            for (int r = 0; r < 4; r++){
                int row = m0 + s*16 + quad*4 + r;
                xb[(size_t)row*256 + 128 + t*16 + l15] = f2h(acc3[s][t][r]);
            }
}

// ---- scatter-mean + transpose, all planes in one launch ----
__global__ __launch_bounds__(1024) void k_psum3(const unsigned short* __restrict__ xb,
        const int* __restrict__ srt, const int* __restrict__ cs,
        float* __restrict__ out){
    __shared__ float ls[32*129];
    int pl = blockIdx.y;
    const int* srtp = srt + (size_t)pl*TT;
    const int* csp  = cs  + (size_t)pl*32769;
    int w = threadIdx.x >> 6, lane = threadIdx.x & 63;
    int c0 = blockIdx.x * 32;
    #pragma unroll
    for (int cc = w; cc < 32; cc += 16){
        int c = c0 + cc;
        int s = csp[c], e = csp[c+1];
        float s0 = 0.f, s1 = 0.f;
        if (s < e){
            int pt = srtp[s];
            for (int i = s; i < e; i++){
                int ptn = (i+1 < e) ? srtp[i+1] : 0;
                unsigned v = ((const unsigned*)(xb + (size_t)pt*256 + 128))[lane];
                s0 += h2f((unsigned short)(v & 0xFFFF));
                s1 += h2f((unsigned short)(v >> 16));
                pt = ptn;
            }
        }
        float rc = (e > s) ? 1.f/(float)(e - s) : 0.f;
        ls[cc*129 + lane*2]     = s0*rc;
        ls[cc*129 + lane*2 + 1] = s1*rc;
    }
    __syncthreads();
    int pb = pl*2 + (c0 >> 14);
    float* o = out + (size_t)pb*128*R2 + (c0 & 16383);
    #pragma unroll
    for (int j = 0; j < 4; j++){
        int lin = j*1024 + threadIdx.x;
        int f = lin >> 5, cc = lin & 31;
        o[(size_t)f*R2 + cc] = ls[cc*129 + f];
    }
}

extern "C" void kernel_launch(void* const* d_in, const int* in_sizes, int n_in,
                              void* d_out, int out_size, void* d_ws, size_t ws_size,
                              hipStream_t stream) {
    const float* p        = (const float*)d_in[0];
    const float* fc_pos_W = (const float*)d_in[1];
    const float* fc_pos_b = (const float*)d_in[2];
    const float* bW0      = (const float*)d_in[3];
    const float* bb0      = (const float*)d_in[4];
    const float* bW1      = (const float*)d_in[5];
    const float* bb1      = (const float*)d_in[6];
    const float* bWs      = (const float*)d_in[7];
    const float* fc_c_W   = (const float*)d_in[8];
    const float* fc_c_b   = (const float*)d_in[9];
    float* out = (float*)d_out;

    char* ws = (char*)d_ws;
    int*            idx   = (int*)ws;                          // 786,432 B
    unsigned short* xbuf  = (unsigned short*)(ws + 786432);    // 33,554,432 B
    int*            srt   = (int*)(ws + 34340864);             // 786,432 B
    int*            cs    = (int*)(ws + 35127296);             // 393,232 B
    int*            cp    = (int*)(ws + 35520528);             // 393,216 B
    unsigned short* wpack = (unsigned short*)(ws + 35913744);  // 851,968 B
    unsigned short* mxp   = (unsigned short*)(ws + 36765712);  // 25,165,824 B

    k_repack<<<1664, 256, 0, stream>>>(bW0, bW1, bWs, fc_c_W, wpack);
    hipMemsetAsync(cp, 0, (size_t)3*32768*4, stream);
    k_idxhist<<<TT/256, 256, 0, stream>>>(p, idx, cp);
    k_scan   <<<3, 1024, 0, stream>>>(cp, cs, cp);
    k_scatter<<<TT/256, 256, 0, stream>>>(idx, cp, srt);

    // resnet 1: fc_pos fused (pin path)
    k_resnet<<<512, 256, 0, stream>>>(xbuf, wpack, bb0, bb1,
            idx, (const unsigned short*)nullptr,
            p, fc_pos_W, fc_pos_b,
            (const unsigned short*)nullptr, (const float*)nullptr);

    for (int i = 1; i < 5; i++){
        k_pool3<<<dim3(8192, 3), 256, 0, stream>>>(xbuf, srt, cs, mxp);
        const unsigned short* wc = (i == 4) ? (wpack + 409600) : (const unsigned short*)nullptr;
        const float* bcp = (i == 4) ? fc_c_b : (const float*)nullptr;
        k_resnet<<<512, 256, 0, stream>>>(xbuf, wpack + (size_t)i*81920,
                bb0 + (size_t)i*128, bb1 + (size_t)i*128,
                idx, mxp,
                (const float*)nullptr, (const float*)nullptr, (const float*)nullptr,
                wc, bcp);
    }

    k_psum3<<<dim3(1024, 3), 1024, 0, stream>>>(xbuf, srt, cs, out);
}